// Round 8
// baseline (1002.433 us; speedup 1.0000x reference)
//
#include <hip/hip_runtime.h>

#define OBS 17
#define ACT 4
#define HID 64
#define BLK 128

// ws layout (floats):
// [0..15]  Qinv (row-major 4x4)
// [16..19] logstd
// [20..23] inv_std = 1/exp(logstd)
// [24]     entropy (uniform across rows)
// [25]     s0
// [26]     sum(logstd) + 2*log(2*pi)   (log_prob constant term)

__device__ __forceinline__ float fast_tanh(float v) {
    // tanh(v) = 1 - 2/(1+exp(2v)); exact saturation at +/-inf, ~1e-7 abs err
    float e = __expf(2.0f * v);
    return 1.0f - 2.0f / (e + 1.0f);
}

__global__ void prep_kernel(const float* __restrict__ L,
                            const float* __restrict__ logstd,
                            const float* __restrict__ s0,
                            float* __restrict__ ws) {
    if (threadIdx.x != 0 || blockIdx.x != 0) return;
    const float LOG2PI = 1.8378770664093453f;
    // Q = tril(L) @ tril(L)^T + 1e-4*I
    float Q[4][4];
    for (int a = 0; a < 4; ++a) {
        for (int b = 0; b < 4; ++b) {
            float s = (a == b) ? 1e-4f : 0.0f;
            int m = a < b ? a : b;
            for (int k = 0; k <= m; ++k) s += L[a * 4 + k] * L[b * 4 + k];
            Q[a][b] = s;
        }
    }
    // Gauss-Jordan inverse (SPD)
    float M[4][8];
    for (int a = 0; a < 4; ++a) {
        for (int b = 0; b < 4; ++b) {
            M[a][b] = Q[a][b];
            M[a][4 + b] = (a == b) ? 1.0f : 0.0f;
        }
    }
    for (int c = 0; c < 4; ++c) {
        float inv = 1.0f / M[c][c];
        for (int j = 0; j < 8; ++j) M[c][j] *= inv;
        for (int r = 0; r < 4; ++r) {
            if (r == c) continue;
            float f = M[r][c];
            for (int j = 0; j < 8; ++j) M[r][j] -= f * M[c][j];
        }
    }
    for (int a = 0; a < 4; ++a)
        for (int b = 0; b < 4; ++b) ws[a * 4 + b] = M[a][4 + b];

    float ent = 0.0f, lsum = 0.0f;
    for (int a = 0; a < 4; ++a) {
        float ls = logstd[a];
        ws[16 + a] = ls;
        ws[20 + a] = 1.0f / __expf(ls);
        ent += 0.5f + 0.5f * LOG2PI + ls;
        lsum += ls;
    }
    ws[24] = ent;
    ws[25] = s0[0];
    ws[26] = lsum + 2.0f * LOG2PI;
}

// All-register version: no LDS. Live set peaks at h[64]+acc2[64]+x[17] ~ 150
// VGPRs. __launch_bounds__(128, 3) -> VGPR cap 512/3 = 170, so the allocator
// can keep everything in registers (round-1 spill trap was a too-low VGPR
// target; round-6 measured the LDS detour costs ~64% stall time at 7 waves/CU).
__global__ __launch_bounds__(BLK, 3) void fused_kernel(
    const float* __restrict__ X, const float* __restrict__ sdfs,
    const float* __restrict__ grads, const float* __restrict__ fx,
    const float* __restrict__ gx, const float* __restrict__ act,
    const float* __restrict__ cW1, const float* __restrict__ cb1,
    const float* __restrict__ cW2, const float* __restrict__ cb2,
    const float* __restrict__ cW3, const float* __restrict__ cb3,
    const float* __restrict__ aW1, const float* __restrict__ ab1,
    const float* __restrict__ aW2, const float* __restrict__ ab2,
    const float* __restrict__ aW3, const float* __restrict__ ab3,
    const float* __restrict__ ws, float* __restrict__ out, int N) {
    const int tid = threadIdx.x;
    const int i = blockIdx.x * BLK + tid;
    if (i >= N) return;

    // ---- observation in registers (compile-time indexed only)
    float x[OBS];
#pragma unroll
    for (int k = 0; k < OBS; ++k) x[k] = X[i * OBS + k];

    float h[HID];     // layer-1 activations (tanh'd in place)
    float acc2[HID];  // layer-2 pre-activations

    // ================= actor =================
#pragma unroll
    for (int j = 0; j < HID; ++j) h[j] = ab1[j];
#pragma unroll
    for (int k = 0; k < OBS; ++k) {
        float xk = x[k];
#pragma unroll
        for (int j = 0; j < HID; ++j) h[j] = fmaf(xk, aW1[k * HID + j], h[j]);
    }
#pragma unroll
    for (int j = 0; j < HID; ++j) h[j] = fast_tanh(h[j]);

#pragma unroll
    for (int j = 0; j < HID; ++j) acc2[j] = ab2[j];
#pragma unroll
    for (int k = 0; k < HID; ++k) {
        float hk = h[k];
#pragma unroll
        for (int j = 0; j < HID; ++j) acc2[j] = fmaf(hk, aW2[k * HID + j], acc2[j]);
    }
    float mean0 = ab3[0], mean1 = ab3[1], mean2 = ab3[2], mean3 = ab3[3];
#pragma unroll
    for (int k = 0; k < HID; ++k) {
        float t = fast_tanh(acc2[k]);
        mean0 = fmaf(t, aW3[k * ACT + 0], mean0);
        mean1 = fmaf(t, aW3[k * ACT + 1], mean1);
        mean2 = fmaf(t, aW3[k * ACT + 2], mean2);
        mean3 = fmaf(t, aW3[k * ACT + 3], mean3);
    }

    // ================= critic (reuse h / acc2) =================
#pragma unroll
    for (int j = 0; j < HID; ++j) h[j] = cb1[j];
#pragma unroll
    for (int k = 0; k < OBS; ++k) {
        float xk = x[k];
#pragma unroll
        for (int j = 0; j < HID; ++j) h[j] = fmaf(xk, cW1[k * HID + j], h[j]);
    }
#pragma unroll
    for (int j = 0; j < HID; ++j) h[j] = fast_tanh(h[j]);

#pragma unroll
    for (int j = 0; j < HID; ++j) acc2[j] = cb2[j];
#pragma unroll
    for (int k = 0; k < HID; ++k) {
        float hk = h[k];
#pragma unroll
        for (int j = 0; j < HID; ++j) acc2[j] = fmaf(hk, cW2[k * HID + j], acc2[j]);
    }
    float value = cb3[0];
#pragma unroll
    for (int k = 0; k < HID; ++k) value = fmaf(fast_tanh(acc2[k]), cW3[k], value);

    // ================= CBF-QP =================
    float G0 = 0.f, G1 = 0.f, G2 = 0.f, G3 = 0.f, gf = 0.f;
    const float* gxr = gx + (size_t)i * (OBS * ACT);
#pragma unroll
    for (int s = 0; s < OBS; ++s) {
        float gr = grads[i * OBS + s];
        gf = fmaf(gr, fx[i * OBS + s], gf);
        G0 = fmaf(-gr, gxr[s * 4 + 0], G0);
        G1 = fmaf(-gr, gxr[s * 4 + 1], G1);
        G2 = fmaf(-gr, gxr[s * 4 + 2], G2);
        G3 = fmaf(-gr, gxr[s * 4 + 3], G3);
    }
    float a0 = act[i * 4 + 0], a1 = act[i * 4 + 1];
    float a2 = act[i * 4 + 2], a3 = act[i * 4 + 3];
    // h = s0 + alpha*sdfs + grads.f_x + grads.g_x.action; last term == -G.action
    float hh = ws[25] + sdfs[i] + gf - (G0 * a0 + G1 * a1 + G2 * a2 + G3 * a3);

    float v0 = ws[0] * G0 + ws[1] * G1 + ws[2] * G2 + ws[3] * G3;
    float v1 = ws[4] * G0 + ws[5] * G1 + ws[6] * G2 + ws[7] * G3;
    float v2 = ws[8] * G0 + ws[9] * G1 + ws[10] * G2 + ws[11] * G3;
    float v3 = ws[12] * G0 + ws[13] * G1 + ws[14] * G2 + ws[15] * G3;
    float denom = G0 * v0 + G1 * v1 + G2 * v2 + G3 * v3;
    float lam = fmaxf(0.0f, -hh / denom);

    float u0 = mean0 - lam * v0;
    float u1 = mean1 - lam * v1;
    float u2 = mean2 - lam * v2;
    float u3 = mean3 - lam * v3;

    // ================= log_prob =================
    float z0 = (a0 - mean0) * ws[20];
    float z1 = (a1 - mean1) * ws[21];
    float z2 = (a2 - mean2) * ws[22];
    float z3 = (a3 - mean3) * ws[23];
    float lp = -0.5f * (z0 * z0 + z1 * z1 + z2 * z2 + z3 * z3) - ws[26];

    // ================= stores =================
    reinterpret_cast<float4*>(out)[i] = make_float4(u0, u1, u2, u3);
    out[4 * N + i] = lp;
    out[5 * N + i] = ws[24];  // entropy (uniform)
    out[6 * N + i] = value;
}

extern "C" void kernel_launch(void* const* d_in, const int* in_sizes, int n_in,
                              void* d_out, int out_size, void* d_ws, size_t ws_size,
                              hipStream_t stream) {
    const float* X     = (const float*)d_in[0];
    const float* sdfs  = (const float*)d_in[1];
    const float* grads = (const float*)d_in[2];
    const float* fx    = (const float*)d_in[3];
    const float* gx    = (const float*)d_in[4];
    const float* act   = (const float*)d_in[5];
    const float* cW1   = (const float*)d_in[6];
    const float* cb1   = (const float*)d_in[7];
    const float* cW2   = (const float*)d_in[8];
    const float* cb2   = (const float*)d_in[9];
    const float* cW3   = (const float*)d_in[10];
    const float* cb3   = (const float*)d_in[11];
    const float* aW1   = (const float*)d_in[12];
    const float* ab1   = (const float*)d_in[13];
    const float* aW2   = (const float*)d_in[14];
    const float* ab2   = (const float*)d_in[15];
    const float* aW3   = (const float*)d_in[16];
    const float* ab3   = (const float*)d_in[17];
    const float* logstd = (const float*)d_in[18];
    const float* L     = (const float*)d_in[19];
    const float* s0    = (const float*)d_in[20];

    float* out = (float*)d_out;
    float* ws  = (float*)d_ws;

    int N = in_sizes[0] / OBS;

    hipLaunchKernelGGL(prep_kernel, dim3(1), dim3(64), 0, stream, L, logstd, s0, ws);
    int blocks = (N + BLK - 1) / BLK;
    hipLaunchKernelGGL(fused_kernel, dim3(blocks), dim3(BLK), 0, stream,
                       X, sdfs, grads, fx, gx, act,
                       cW1, cb1, cW2, cb2, cW3, cb3,
                       aW1, ab1, aW2, ab2, aW3, ab3,
                       ws, out, N);
}

// Round 9
// 359.685 us; speedup vs baseline: 2.7870x; 2.7870x over previous
//
#include <hip/hip_runtime.h>

#define OBS 17
#define ACT 4
#define HID 64
#define BLK 128

// ws layout (floats):
// [0..15]  Qinv (row-major 4x4)
// [16..19] logstd
// [20..23] inv_std = 1/exp(logstd)
// [24]     entropy (uniform across rows)
// [25]     s0
// [26]     sum(logstd) + 2*log(2*pi)   (log_prob constant term)

__device__ __forceinline__ float fast_tanh(float v) {
    // tanh(v) = 1 - 2/(1+exp(2v)); exact saturation at +/-inf, ~1e-7 abs err
    float e = __expf(2.0f * v);
    return 1.0f - 2.0f / (e + 1.0f);
}

__global__ void prep_kernel(const float* __restrict__ L,
                            const float* __restrict__ logstd,
                            const float* __restrict__ s0,
                            float* __restrict__ ws) {
    if (threadIdx.x != 0 || blockIdx.x != 0) return;
    const float LOG2PI = 1.8378770664093453f;
    // Q = tril(L) @ tril(L)^T + 1e-4*I
    float Q[4][4];
    for (int a = 0; a < 4; ++a) {
        for (int b = 0; b < 4; ++b) {
            float s = (a == b) ? 1e-4f : 0.0f;
            int m = a < b ? a : b;
            for (int k = 0; k <= m; ++k) s += L[a * 4 + k] * L[b * 4 + k];
            Q[a][b] = s;
        }
    }
    // Gauss-Jordan inverse (SPD)
    float M[4][8];
    for (int a = 0; a < 4; ++a) {
        for (int b = 0; b < 4; ++b) {
            M[a][b] = Q[a][b];
            M[a][4 + b] = (a == b) ? 1.0f : 0.0f;
        }
    }
    for (int c = 0; c < 4; ++c) {
        float inv = 1.0f / M[c][c];
        for (int j = 0; j < 8; ++j) M[c][j] *= inv;
        for (int r = 0; r < 4; ++r) {
            if (r == c) continue;
            float f = M[r][c];
            for (int j = 0; j < 8; ++j) M[r][j] -= f * M[c][j];
        }
    }
    for (int a = 0; a < 4; ++a)
        for (int b = 0; b < 4; ++b) ws[a * 4 + b] = M[a][4 + b];

    float ent = 0.0f, lsum = 0.0f;
    for (int a = 0; a < 4; ++a) {
        float ls = logstd[a];
        ws[16 + a] = ls;
        ws[20 + a] = 1.0f / __expf(ls);
        ent += 0.5f + 0.5f * LOG2PI + ls;
        lsum += ls;
    }
    ws[24] = ent;
    ws[25] = s0[0];
    ws[26] = lsum + 2.0f * LOG2PI;
}

// Fused layer1->layer2: h_j is computed from x (17 FMAs + tanh) and consumed
// immediately into the 64 static-indexed acc2 FMAs, so NO h[64] array exists.
// Peak live set ~ x(17)+acc2(64)+temps ~= 90 floats -- inside the allocator's
// revealed comfort zone (rounds 1/6/8 chose 80-92 VGPRs). No LDS, no ds_read.
__global__ __launch_bounds__(BLK, 2) void fused_kernel(
    const float* __restrict__ X, const float* __restrict__ sdfs,
    const float* __restrict__ grads, const float* __restrict__ fx,
    const float* __restrict__ gx, const float* __restrict__ act,
    const float* __restrict__ cW1, const float* __restrict__ cb1,
    const float* __restrict__ cW2, const float* __restrict__ cb2,
    const float* __restrict__ cW3, const float* __restrict__ cb3,
    const float* __restrict__ aW1, const float* __restrict__ ab1,
    const float* __restrict__ aW2, const float* __restrict__ ab2,
    const float* __restrict__ aW3, const float* __restrict__ ab3,
    const float* __restrict__ ws, float* __restrict__ out, int N) {
    const int tid = threadIdx.x;
    const int i = blockIdx.x * BLK + tid;
    if (i >= N) return;

    // ---- observation in registers (compile-time indexed only)
    float x[OBS];
#pragma unroll
    for (int k = 0; k < OBS; ++k) x[k] = X[i * OBS + k];

    float acc2[HID];  // the ONLY 64-float array; reused by actor then critic

    // ================= actor: fused L1->L2 =================
#pragma unroll
    for (int j = 0; j < HID; ++j) acc2[j] = ab2[j];
#pragma unroll 4
    for (int j = 0; j < HID; ++j) {  // rolled over hidden-1 units
        float s = ab1[j];
#pragma unroll
        for (int k = 0; k < OBS; ++k) s = fmaf(x[k], aW1[k * HID + j], s);
        float hj = fast_tanh(s);
#pragma unroll
        for (int o = 0; o < HID; ++o) acc2[o] = fmaf(hj, aW2[j * HID + o], acc2[o]);
    }
    float mean0 = ab3[0], mean1 = ab3[1], mean2 = ab3[2], mean3 = ab3[3];
#pragma unroll
    for (int k = 0; k < HID; ++k) {
        float t = fast_tanh(acc2[k]);
        mean0 = fmaf(t, aW3[k * ACT + 0], mean0);
        mean1 = fmaf(t, aW3[k * ACT + 1], mean1);
        mean2 = fmaf(t, aW3[k * ACT + 2], mean2);
        mean3 = fmaf(t, aW3[k * ACT + 3], mean3);
    }

    // ================= critic: fused L1->L2 (reuse acc2) =================
#pragma unroll
    for (int j = 0; j < HID; ++j) acc2[j] = cb2[j];
#pragma unroll 4
    for (int j = 0; j < HID; ++j) {
        float s = cb1[j];
#pragma unroll
        for (int k = 0; k < OBS; ++k) s = fmaf(x[k], cW1[k * HID + j], s);
        float hj = fast_tanh(s);
#pragma unroll
        for (int o = 0; o < HID; ++o) acc2[o] = fmaf(hj, cW2[j * HID + o], acc2[o]);
    }
    float value = cb3[0];
#pragma unroll
    for (int k = 0; k < HID; ++k) value = fmaf(fast_tanh(acc2[k]), cW3[k], value);

    // ================= CBF-QP =================
    float G0 = 0.f, G1 = 0.f, G2 = 0.f, G3 = 0.f, gf = 0.f;
    const float* gxr = gx + (size_t)i * (OBS * ACT);
#pragma unroll
    for (int s = 0; s < OBS; ++s) {
        float gr = grads[i * OBS + s];
        gf = fmaf(gr, fx[i * OBS + s], gf);
        G0 = fmaf(-gr, gxr[s * 4 + 0], G0);
        G1 = fmaf(-gr, gxr[s * 4 + 1], G1);
        G2 = fmaf(-gr, gxr[s * 4 + 2], G2);
        G3 = fmaf(-gr, gxr[s * 4 + 3], G3);
    }
    float a0 = act[i * 4 + 0], a1 = act[i * 4 + 1];
    float a2 = act[i * 4 + 2], a3 = act[i * 4 + 3];
    // h = s0 + alpha*sdfs + grads.f_x + grads.g_x.action; last term == -G.action
    float hh = ws[25] + sdfs[i] + gf - (G0 * a0 + G1 * a1 + G2 * a2 + G3 * a3);

    float v0 = ws[0] * G0 + ws[1] * G1 + ws[2] * G2 + ws[3] * G3;
    float v1 = ws[4] * G0 + ws[5] * G1 + ws[6] * G2 + ws[7] * G3;
    float v2 = ws[8] * G0 + ws[9] * G1 + ws[10] * G2 + ws[11] * G3;
    float v3 = ws[12] * G0 + ws[13] * G1 + ws[14] * G2 + ws[15] * G3;
    float denom = G0 * v0 + G1 * v1 + G2 * v2 + G3 * v3;
    float lam = fmaxf(0.0f, -hh / denom);

    float u0 = mean0 - lam * v0;
    float u1 = mean1 - lam * v1;
    float u2 = mean2 - lam * v2;
    float u3 = mean3 - lam * v3;

    // ================= log_prob =================
    float z0 = (a0 - mean0) * ws[20];
    float z1 = (a1 - mean1) * ws[21];
    float z2 = (a2 - mean2) * ws[22];
    float z3 = (a3 - mean3) * ws[23];
    float lp = -0.5f * (z0 * z0 + z1 * z1 + z2 * z2 + z3 * z3) - ws[26];

    // ================= stores =================
    reinterpret_cast<float4*>(out)[i] = make_float4(u0, u1, u2, u3);
    out[4 * N + i] = lp;
    out[5 * N + i] = ws[24];  // entropy (uniform)
    out[6 * N + i] = value;
}

extern "C" void kernel_launch(void* const* d_in, const int* in_sizes, int n_in,
                              void* d_out, int out_size, void* d_ws, size_t ws_size,
                              hipStream_t stream) {
    const float* X     = (const float*)d_in[0];
    const float* sdfs  = (const float*)d_in[1];
    const float* grads = (const float*)d_in[2];
    const float* fx    = (const float*)d_in[3];
    const float* gx    = (const float*)d_in[4];
    const float* act   = (const float*)d_in[5];
    const float* cW1   = (const float*)d_in[6];
    const float* cb1   = (const float*)d_in[7];
    const float* cW2   = (const float*)d_in[8];
    const float* cb2   = (const float*)d_in[9];
    const float* cW3   = (const float*)d_in[10];
    const float* cb3   = (const float*)d_in[11];
    const float* aW1   = (const float*)d_in[12];
    const float* ab1   = (const float*)d_in[13];
    const float* aW2   = (const float*)d_in[14];
    const float* ab2   = (const float*)d_in[15];
    const float* aW3   = (const float*)d_in[16];
    const float* ab3   = (const float*)d_in[17];
    const float* logstd = (const float*)d_in[18];
    const float* L     = (const float*)d_in[19];
    const float* s0    = (const float*)d_in[20];

    float* out = (float*)d_out;
    float* ws  = (float*)d_ws;

    int N = in_sizes[0] / OBS;

    hipLaunchKernelGGL(prep_kernel, dim3(1), dim3(64), 0, stream, L, logstd, s0, ws);
    int blocks = (N + BLK - 1) / BLK;
    hipLaunchKernelGGL(fused_kernel, dim3(blocks), dim3(BLK), 0, stream,
                       X, sdfs, grads, fx, gx, act,
                       cW1, cb1, cW2, cb2, cW3, cb3,
                       aW1, ab1, aW2, ab2, aW3, ab3,
                       ws, out, N);
}

// Round 10
// 248.686 us; speedup vs baseline: 4.0309x; 1.4463x over previous
//
#include <hip/hip_runtime.h>

#define OBS 17
#define ACT 4
#define HID 64
#define BLK 64        // one wave per block
#define HSTRIDE 68    // shorts per LDS row: 64 data + 4 pad (136 B, 8B-aligned, bank-spread)

using bf16x8 = __attribute__((ext_vector_type(8))) short;  // 8 bf16 = 4 VGPR (MFMA A/B frag)
using f32x4  = __attribute__((ext_vector_type(4))) float;  // MFMA C/D frag
typedef unsigned long long ull;

// ws layout:
//   float [0..15]  Qinv, [16..19] logstd, [20..23] inv_std, [24] entropy,
//         [25] s0, [26] lp const
//   ushort[64 ...] W2 B-fragments: frag f = net*8 + ct*2 + q, lane l, elem i:
//         wsu[64 + (f*64 + l)*8 + i] = bf16(W2net[(32q + 8*(l>>4) + i)*64 + 16ct + (l&15)])

__device__ __forceinline__ float fast_tanh(float v) {
    float e = __expf(2.0f * v);
    return 1.0f - 2.0f / (e + 1.0f);
}
__device__ __forceinline__ unsigned short f2bf(float f) {  // RNE fp32->bf16
    unsigned int u = __float_as_uint(f);
    u = (u + 0x7FFFu + ((u >> 16) & 1u)) >> 16;
    return (unsigned short)u;
}
__device__ __forceinline__ float bf2f(unsigned short s) {
    return __uint_as_float(((unsigned int)s) << 16);
}

__global__ void prep_kernel(const float* __restrict__ L,
                            const float* __restrict__ logstd,
                            const float* __restrict__ s0,
                            const float* __restrict__ aW2,
                            const float* __restrict__ cW2,
                            float* __restrict__ ws) {
    const int t = threadIdx.x;
    // ---- pack W2 (both nets) into MFMA B-fragment lane order (coalesced 16B/lane at runtime)
    unsigned short* wsu = (unsigned short*)ws;
    const int g = t >> 4, r = t & 15;
    for (int n = 0; n < 2; ++n) {
        const float* W = n ? cW2 : aW2;
        for (int ct = 0; ct < 4; ++ct)
            for (int q = 0; q < 2; ++q) {
                int f = n * 8 + ct * 2 + q;
                for (int i = 0; i < 8; ++i)
                    wsu[64 + (f * 64 + t) * 8 + i] =
                        f2bf(W[(32 * q + 8 * g + i) * HID + 16 * ct + r]);
            }
    }
    if (t != 0) return;
    const float LOG2PI = 1.8378770664093453f;
    float Q[4][4];
    for (int a = 0; a < 4; ++a)
        for (int b = 0; b < 4; ++b) {
            float s = (a == b) ? 1e-4f : 0.0f;
            int m = a < b ? a : b;
            for (int k = 0; k <= m; ++k) s += L[a * 4 + k] * L[b * 4 + k];
            Q[a][b] = s;
        }
    float M[4][8];
    for (int a = 0; a < 4; ++a)
        for (int b = 0; b < 4; ++b) {
            M[a][b] = Q[a][b];
            M[a][4 + b] = (a == b) ? 1.0f : 0.0f;
        }
    for (int c = 0; c < 4; ++c) {
        float inv = 1.0f / M[c][c];
        for (int j = 0; j < 8; ++j) M[c][j] *= inv;
        for (int rr = 0; rr < 4; ++rr) {
            if (rr == c) continue;
            float f = M[rr][c];
            for (int j = 0; j < 8; ++j) M[rr][j] -= f * M[c][j];
        }
    }
    for (int a = 0; a < 4; ++a)
        for (int b = 0; b < 4; ++b) ws[a * 4 + b] = M[a][4 + b];
    float ent = 0.0f, lsum = 0.0f;
    for (int a = 0; a < 4; ++a) {
        float ls = logstd[a];
        ws[16 + a] = ls;
        ws[20 + a] = 1.0f / __expf(ls);
        ent += 0.5f + 0.5f * LOG2PI + ls;
        lsum += ls;
    }
    ws[24] = ent;
    ws[25] = s0[0];
    ws[26] = lsum + 2.0f * LOG2PI;
}

// L1 in fp32 VALU (h[64] = the single validated no-spill array), then bf16 ->
// LDS tile, L2 via mfma_f32_16x16x32_bf16 (4 row-tiles x 4 col-tiles x 2 K),
// tanh(C) written back IN PLACE (row-tiles disjoint). Caller reads h2 rows.
__device__ __forceinline__ void mlp_to_h2(
    const float* __restrict__ W1, const float* __restrict__ b1,
    const float* __restrict__ b2, const unsigned short* __restrict__ wsu,
    int net, const float* x, unsigned short* hs, int tid) {
    const int g = tid >> 4, r = tid & 15;

    float h[HID];
#pragma unroll
    for (int j = 0; j < HID; ++j) h[j] = b1[j];
#pragma unroll
    for (int k = 0; k < OBS; ++k) {
        float xk = x[k];
#pragma unroll
        for (int j = 0; j < HID; ++j) h[j] = fmaf(xk, W1[k * HID + j], h[j]);
    }
    __syncthreads();  // previous phase's LDS reads complete before overwrite
#pragma unroll
    for (int j = 0; j < HID; j += 4) {  // tanh -> bf16 -> own LDS row (b64 writes)
        ull w = (ull)f2bf(fast_tanh(h[j]))
              | ((ull)f2bf(fast_tanh(h[j + 1])) << 16)
              | ((ull)f2bf(fast_tanh(h[j + 2])) << 32)
              | ((ull)f2bf(fast_tanh(h[j + 3])) << 48);
        *(ull*)&hs[tid * HSTRIDE + j] = w;
    }
    __syncthreads();

    // B fragments for this net: one coalesced 16B load per lane per frag
    bf16x8 B[4][2];
#pragma unroll
    for (int ct = 0; ct < 4; ++ct)
#pragma unroll
        for (int q = 0; q < 2; ++q) {
            int f = net * 8 + ct * 2 + q;
            B[ct][q] = *(const bf16x8*)(wsu + 64 + (size_t)(f * 64 + tid) * 8);
        }
    float bias[4];
#pragma unroll
    for (int ct = 0; ct < 4; ++ct) bias[ct] = b2[16 * ct + r];

#pragma unroll
    for (int rt = 0; rt < 4; ++rt) {
        const int arow = 16 * rt + r;
        union { ull u[2]; bf16x8 v; } ua0, ua1;
        ua0.u[0] = *(const ull*)&hs[arow * HSTRIDE + 8 * g];
        ua0.u[1] = *(const ull*)&hs[arow * HSTRIDE + 8 * g + 4];
        ua1.u[0] = *(const ull*)&hs[arow * HSTRIDE + 32 + 8 * g];
        ua1.u[1] = *(const ull*)&hs[arow * HSTRIDE + 32 + 8 * g + 4];
#pragma unroll
        for (int ct = 0; ct < 4; ++ct) {
            f32x4 c = {bias[ct], bias[ct], bias[ct], bias[ct]};
            c = __builtin_amdgcn_mfma_f32_16x16x32_bf16(ua0.v, B[ct][0], c, 0, 0, 0);
            c = __builtin_amdgcn_mfma_f32_16x16x32_bf16(ua1.v, B[ct][1], c, 0, 0, 0);
            // C/D: col = lane&15, row = (lane>>4)*4 + reg  [m89-verified]
#pragma unroll
            for (int reg = 0; reg < 4; ++reg)
                hs[(16 * rt + 4 * g + reg) * HSTRIDE + 16 * ct + r] =
                    f2bf(fast_tanh(c[reg]));
        }
    }
    __syncthreads();
}

__global__ __launch_bounds__(BLK, 2) void fused_kernel(
    const float* __restrict__ X, const float* __restrict__ sdfs,
    const float* __restrict__ grads, const float* __restrict__ fx,
    const float* __restrict__ gx, const float* __restrict__ act,
    const float* __restrict__ cW1, const float* __restrict__ cb1,
    const float* __restrict__ cb2, const float* __restrict__ cW3,
    const float* __restrict__ cb3,
    const float* __restrict__ aW1, const float* __restrict__ ab1,
    const float* __restrict__ ab2, const float* __restrict__ aW3,
    const float* __restrict__ ab3,
    const float* __restrict__ ws, float* __restrict__ out, int N) {
    __shared__ unsigned short hs[64 * HSTRIDE];  // 8704 B

    const int tid = threadIdx.x;
    const int row = blockIdx.x * BLK + tid;
    const bool live = row < N;
    const int lrow = live ? row : (N - 1);
    const unsigned short* wsu = (const unsigned short*)ws;

    float x[OBS];
#pragma unroll
    for (int k = 0; k < OBS; ++k) x[k] = X[lrow * OBS + k];

    // ================= actor =================
    mlp_to_h2(aW1, ab1, ab2, wsu, 0, x, hs, tid);
    float mean0 = ab3[0], mean1 = ab3[1], mean2 = ab3[2], mean3 = ab3[3];
#pragma unroll
    for (int k = 0; k < HID; k += 4) {
        ull w = *(const ull*)&hs[tid * HSTRIDE + k];
#pragma unroll
        for (int m = 0; m < 4; ++m) {
            float t = bf2f((unsigned short)(w >> (16 * m)));
            mean0 = fmaf(t, aW3[(k + m) * ACT + 0], mean0);
            mean1 = fmaf(t, aW3[(k + m) * ACT + 1], mean1);
            mean2 = fmaf(t, aW3[(k + m) * ACT + 2], mean2);
            mean3 = fmaf(t, aW3[(k + m) * ACT + 3], mean3);
        }
    }

    // ================= critic =================
    mlp_to_h2(cW1, cb1, cb2, wsu, 1, x, hs, tid);
    float value = cb3[0];
#pragma unroll
    for (int k = 0; k < HID; k += 4) {
        ull w = *(const ull*)&hs[tid * HSTRIDE + k];
#pragma unroll
        for (int m = 0; m < 4; ++m)
            value = fmaf(bf2f((unsigned short)(w >> (16 * m))), cW3[k + m], value);
    }

    // ================= CBF-QP =================
    float G0 = 0.f, G1 = 0.f, G2 = 0.f, G3 = 0.f, gf = 0.f;
    const float* gxr = gx + (size_t)lrow * (OBS * ACT);
#pragma unroll
    for (int s = 0; s < OBS; ++s) {
        float gr = grads[lrow * OBS + s];
        gf = fmaf(gr, fx[lrow * OBS + s], gf);
        G0 = fmaf(-gr, gxr[s * 4 + 0], G0);
        G1 = fmaf(-gr, gxr[s * 4 + 1], G1);
        G2 = fmaf(-gr, gxr[s * 4 + 2], G2);
        G3 = fmaf(-gr, gxr[s * 4 + 3], G3);
    }
    float a0 = act[lrow * 4 + 0], a1 = act[lrow * 4 + 1];
    float a2 = act[lrow * 4 + 2], a3 = act[lrow * 4 + 3];
    float hh = ws[25] + sdfs[lrow] + gf - (G0 * a0 + G1 * a1 + G2 * a2 + G3 * a3);

    float v0 = ws[0] * G0 + ws[1] * G1 + ws[2] * G2 + ws[3] * G3;
    float v1 = ws[4] * G0 + ws[5] * G1 + ws[6] * G2 + ws[7] * G3;
    float v2 = ws[8] * G0 + ws[9] * G1 + ws[10] * G2 + ws[11] * G3;
    float v3 = ws[12] * G0 + ws[13] * G1 + ws[14] * G2 + ws[15] * G3;
    float denom = G0 * v0 + G1 * v1 + G2 * v2 + G3 * v3;
    float lam = fmaxf(0.0f, -hh / denom);

    float u0 = mean0 - lam * v0;
    float u1 = mean1 - lam * v1;
    float u2 = mean2 - lam * v2;
    float u3 = mean3 - lam * v3;

    float z0 = (a0 - mean0) * ws[20];
    float z1 = (a1 - mean1) * ws[21];
    float z2 = (a2 - mean2) * ws[22];
    float z3 = (a3 - mean3) * ws[23];
    float lp = -0.5f * (z0 * z0 + z1 * z1 + z2 * z2 + z3 * z3) - ws[26];

    if (live) {
        reinterpret_cast<float4*>(out)[row] = make_float4(u0, u1, u2, u3);
        out[4 * N + row] = lp;
        out[5 * N + row] = ws[24];
        out[6 * N + row] = value;
    }
}

extern "C" void kernel_launch(void* const* d_in, const int* in_sizes, int n_in,
                              void* d_out, int out_size, void* d_ws, size_t ws_size,
                              hipStream_t stream) {
    const float* X     = (const float*)d_in[0];
    const float* sdfs  = (const float*)d_in[1];
    const float* grads = (const float*)d_in[2];
    const float* fx    = (const float*)d_in[3];
    const float* gx    = (const float*)d_in[4];
    const float* act   = (const float*)d_in[5];
    const float* cW1   = (const float*)d_in[6];
    const float* cb1   = (const float*)d_in[7];
    const float* cW2   = (const float*)d_in[8];
    const float* cb2   = (const float*)d_in[9];
    const float* cW3   = (const float*)d_in[10];
    const float* cb3   = (const float*)d_in[11];
    const float* aW1   = (const float*)d_in[12];
    const float* ab1   = (const float*)d_in[13];
    const float* aW2   = (const float*)d_in[14];
    const float* ab2   = (const float*)d_in[15];
    const float* aW3   = (const float*)d_in[16];
    const float* ab3   = (const float*)d_in[17];
    const float* logstd = (const float*)d_in[18];
    const float* L     = (const float*)d_in[19];
    const float* s0    = (const float*)d_in[20];

    float* out = (float*)d_out;
    float* ws  = (float*)d_ws;

    int N = in_sizes[0] / OBS;

    hipLaunchKernelGGL(prep_kernel, dim3(1), dim3(64), 0, stream,
                       L, logstd, s0, aW2, cW2, ws);
    int blocks = (N + BLK - 1) / BLK;
    hipLaunchKernelGGL(fused_kernel, dim3(blocks), dim3(BLK), 0, stream,
                       X, sdfs, grads, fx, gx, act,
                       cW1, cb1, cb2, cW3, cb3,
                       aW1, ab1, ab2, aW3, ab3,
                       ws, out, N);
}